// Round 2
// baseline (412.867 us; speedup 1.0000x reference)
//
#include <hip/hip_runtime.h>

// y = relu(x @ W1 + b1) @ W2 + b2
// x: [B,64] fp32, W1: [64,32], b1: [32], W2: [32,16], b2: [16], y: [B,16], B=1M.
//
// R1 showed 170 us, HBM 27%, VALU 37% -> latency-bound: per-lane 256-B-strided
// row loads (64 lines/instr) + 40-VGPR load/use serialization.
//
// R2 design: wave-private LDS staging.
//  - Each wave owns 64 rows. All 16 global float4 loads (both k-phases) issue
//    up front, fully coalesced (8 contiguous 128-B chunks per instruction).
//  - Data round-trips through 8 KB wave-private LDS (XOR-swizzled so both the
//    scatter-write and the per-row read hit all 32 banks once per 8 lanes).
//  - Wave-private => no __syncthreads, only s_waitcnt lgkmcnt(0) + wave_barrier.
//  - k split in two 32-col phases: LDS = 4 waves * 8 KB = 32 KB/block.
//  - Weights indexed wave-uniformly -> s_load broadcast, FMAs are v_fmac v,s,v.
// Floor: max(mem ~55 us @ 6.3 TB/s, VALU ~36 us) -> predict 55-75 us.

#define N_IN  64
#define N_MID 32
#define N_OUT 16
#define BLOCK 256

__global__ __launch_bounds__(BLOCK, 4) void livenet_mlp_kernel(
    const float* __restrict__ x,
    const float* __restrict__ W1,
    const float* __restrict__ b1,
    const float* __restrict__ W2,
    const float* __restrict__ b2,
    float* __restrict__ y)
{
    // per-wave: 64 rows x 32 cols = 8 float4/row, XOR-swizzled
    __shared__ float4 tile[4][512];   // 32 KB

    const int lane = threadIdx.x & 63;
    const int wave = threadIdx.x >> 6;
    const int rowbase = blockIdx.x * BLOCK + wave * 64;

    const float4* __restrict__ xg = reinterpret_cast<const float4*>(x);

    // ---- Issue ALL 16 coalesced global loads before any wait.
    float4 v0[8], v1[8];
#pragma unroll
    for (int i = 0; i < 8; ++i) {
        const int f  = i * 64 + lane;   // flat float4 id in this wave's phase-tile
        const int r  = f >> 3;          // row 0..63
        const int c4 = f & 7;           // float4-col 0..7
        const size_t g = (size_t)(rowbase + r) * 16 + c4;
        v0[i] = xg[g];                  // cols  0..31
        v1[i] = xg[g + 8];              // cols 32..63
    }

    float h[N_MID];
#pragma unroll
    for (int j = 0; j < N_MID; ++j) h[j] = b1[j];

    // ================= phase 0: k = 0..31 =================
#pragma unroll
    for (int i = 0; i < 8; ++i) {
        const int f  = i * 64 + lane;
        const int r  = f >> 3;
        const int c4 = f & 7;
        tile[wave][r * 8 + (c4 ^ (r & 7))] = v0[i];
    }
    asm volatile("s_waitcnt lgkmcnt(0)" ::: "memory");
    __builtin_amdgcn_wave_barrier();

#pragma unroll
    for (int c4 = 0; c4 < 8; ++c4) {
        const float4 xv = tile[wave][lane * 8 + (c4 ^ (lane & 7))];
        const int k = c4 * 4;
#pragma unroll
        for (int j = 0; j < N_MID; ++j)
            h[j] = __builtin_fmaf(xv.x, W1[(k + 0) * N_MID + j], h[j]);
#pragma unroll
        for (int j = 0; j < N_MID; ++j)
            h[j] = __builtin_fmaf(xv.y, W1[(k + 1) * N_MID + j], h[j]);
#pragma unroll
        for (int j = 0; j < N_MID; ++j)
            h[j] = __builtin_fmaf(xv.z, W1[(k + 2) * N_MID + j], h[j]);
#pragma unroll
        for (int j = 0; j < N_MID; ++j)
            h[j] = __builtin_fmaf(xv.w, W1[(k + 3) * N_MID + j], h[j]);
    }
    __builtin_amdgcn_wave_barrier();   // keep phase-1 writes after phase-0 reads

    // ================= phase 1: k = 32..63 =================
#pragma unroll
    for (int i = 0; i < 8; ++i) {
        const int f  = i * 64 + lane;
        const int r  = f >> 3;
        const int c4 = f & 7;
        tile[wave][r * 8 + (c4 ^ (r & 7))] = v1[i];
    }
    asm volatile("s_waitcnt lgkmcnt(0)" ::: "memory");
    __builtin_amdgcn_wave_barrier();

#pragma unroll
    for (int c4 = 0; c4 < 8; ++c4) {
        const float4 xv = tile[wave][lane * 8 + (c4 ^ (lane & 7))];
        const int k = 32 + c4 * 4;
#pragma unroll
        for (int j = 0; j < N_MID; ++j)
            h[j] = __builtin_fmaf(xv.x, W1[(k + 0) * N_MID + j], h[j]);
#pragma unroll
        for (int j = 0; j < N_MID; ++j)
            h[j] = __builtin_fmaf(xv.y, W1[(k + 1) * N_MID + j], h[j]);
#pragma unroll
        for (int j = 0; j < N_MID; ++j)
            h[j] = __builtin_fmaf(xv.z, W1[(k + 2) * N_MID + j], h[j]);
#pragma unroll
        for (int j = 0; j < N_MID; ++j)
            h[j] = __builtin_fmaf(xv.w, W1[(k + 3) * N_MID + j], h[j]);
    }

    // ================= epilogue =================
#pragma unroll
    for (int j = 0; j < N_MID; ++j) h[j] = fmaxf(h[j], 0.0f);

    float yv[N_OUT];
#pragma unroll
    for (int o = 0; o < N_OUT; ++o) yv[o] = b2[o];
#pragma unroll
    for (int j = 0; j < N_MID; ++j) {
        const float hj = h[j];
#pragma unroll
        for (int o = 0; o < N_OUT; ++o)
            yv[o] = __builtin_fmaf(hj, W2[j * N_OUT + o], yv[o]);
    }

    float4* __restrict__ yg =
        reinterpret_cast<float4*>(y + (size_t)(rowbase + lane) * N_OUT);
#pragma unroll
    for (int i = 0; i < 4; ++i)
        yg[i] = make_float4(yv[4 * i + 0], yv[4 * i + 1], yv[4 * i + 2], yv[4 * i + 3]);
}

extern "C" void kernel_launch(void* const* d_in, const int* in_sizes, int n_in,
                              void* d_out, int out_size, void* d_ws, size_t ws_size,
                              hipStream_t stream) {
    const float* x  = (const float*)d_in[0];
    const float* W1 = (const float*)d_in[1];
    const float* b1 = (const float*)d_in[2];
    const float* W2 = (const float*)d_in[3];
    const float* b2 = (const float*)d_in[4];
    float* yp = (float*)d_out;

    const int nrows = in_sizes[0] / N_IN;        // 1048576, divisible by 256
    const int grid = nrows / BLOCK;              // 4096
    livenet_mlp_kernel<<<grid, BLOCK, 0, stream>>>(x, W1, b1, W2, b2, yp);
}

// Round 3
// 378.824 us; speedup vs baseline: 1.0899x; 1.0899x over previous
//
#include <hip/hip_runtime.h>

// y = relu(x @ W1 + b1) @ W2 + b2
// x:[1M,64] f32, W1:[64,32], b1:[32], W2:[32,16], b2:[16], y:[1M,16] f32.
//
// R1/R2 (~155-170 us) were stalled on scalar weight re-streaming: W1 doesn't
// fit in SGPRs, so row-per-lane forces s_load streams + lgkmcnt waits through
// the whole FMA loop (and R2's ds_reads shared that counter -> no win).
//
// R3: MFMA. Weights become per-lane B-fragments loaded ONCE into VGPRs.
//  - fp32 emulated as bf16 hi+lo, 3-pass (AhBh + AlBh + AhBl): rel err ~2^-16.
//  - Tile = 16 rows. Layer1: M16 K64(2 steps) N32(2 tiles) -> 12 MFMAs.
//    Layer2: M16 K32 N16 -> 3 MFMAs.  mfma_f32_16x16x32_bf16.
//  - A-frag: lane holds A[m=lane&15][k=(lane>>4)*8+j] -> x loads are 2x
//    dwordx4 per k-step, coalesced (16 rows x 256B contiguous per tile).
//  - C/D: col=lane&15, row=(lane>>4)*4+reg (m89-verified).
//  - h: C-layout -> A-layout via wave-private LDS (stride 33: conflict-free
//    writes, <=2-way reads = free). No __syncthreads. No s_loads in loop.
//  - bias+relu applied in fp32 on the LDS readback; b2 added at the C write.
// Floor: mem 53 us (336 MB @ 6.3 TB/s) >> matrix ~8 us, VALU ~15-20 us.

#define BLOCK 256
#define TPW   8          // tiles (of 16 rows) per wave
#define LSTR  33         // LDS row stride (floats)

typedef __attribute__((ext_vector_type(8))) short bf16x8;
typedef __attribute__((ext_vector_type(4))) float f32x4;

static __device__ __forceinline__ short f2bf(float f) {
    unsigned u = __float_as_uint(f);
    u += 0x7FFFu + ((u >> 16) & 1u);          // RNE
    return (short)(u >> 16);
}
static __device__ __forceinline__ float bf2f(short s) {
    return __uint_as_float(((unsigned)(unsigned short)s) << 16);
}

__global__ __launch_bounds__(BLOCK, 3) void livenet_mlp_mfma(
    const float* __restrict__ x,
    const float* __restrict__ W1,
    const float* __restrict__ b1,
    const float* __restrict__ W2,
    const float* __restrict__ b2,
    float* __restrict__ y)
{
    __shared__ float hlds[4][16 * LSTR];      // 8448 B total

    const int lane = threadIdx.x & 63;
    const int wave = threadIdx.x >> 6;
    const int l15  = lane & 15;
    const int q    = lane >> 4;

    // ---------- one-time: weight/bias fragments into VGPRs ----------
    bf16x8 w1h[2][2], w1l[2][2];
#pragma unroll
    for (int s = 0; s < 2; ++s)
#pragma unroll
        for (int t = 0; t < 2; ++t)
#pragma unroll
            for (int j = 0; j < 8; ++j) {
                float w = W1[(32 * s + q * 8 + j) * 32 + 16 * t + l15];
                short hh = f2bf(w);
                w1h[s][t][j] = hh;
                w1l[s][t][j] = f2bf(w - bf2f(hh));
            }
    bf16x8 w2h, w2l;
#pragma unroll
    for (int j = 0; j < 8; ++j) {
        float w = W2[(q * 8 + j) * 16 + l15];
        short hh = f2bf(w);
        w2h[j] = hh;
        w2l[j] = f2bf(w - bf2f(hh));
    }
    float b1v[8];
#pragma unroll
    for (int j = 0; j < 8; ++j) b1v[j] = b1[q * 8 + j];
    const float b2v = b2[l15];

    // ---------- tile loop ----------
    const long tile0 = ((long)blockIdx.x * 4 + wave) * TPW;
    const float* xb = x + (size_t)tile0 * 1024 + (size_t)l15 * 64 + q * 8;
    float* hw = &hlds[wave][0];

    // prefetch tile 0: per lane 8 floats at k-step 0 (+0) and k-step 1 (+32)
    f32x4 c0 = *(const f32x4*)(xb + 0);
    f32x4 c1 = *(const f32x4*)(xb + 4);
    f32x4 c2 = *(const f32x4*)(xb + 32);
    f32x4 c3 = *(const f32x4*)(xb + 36);

    for (int t = 0; t < TPW; ++t) {
        // ---- prefetch next tile (last iter: reload same, harmless) ----
        const int tn = (t + 1 < TPW) ? (t + 1) : t;
        const float* xn = xb + (size_t)tn * 1024;
        f32x4 n0 = *(const f32x4*)(xn + 0);
        f32x4 n1 = *(const f32x4*)(xn + 4);
        f32x4 n2 = *(const f32x4*)(xn + 32);
        f32x4 n3 = *(const f32x4*)(xn + 36);

        // ---- x -> bf16 hi/lo A-fragments ----
        float xs[16];
#pragma unroll
        for (int j = 0; j < 4; ++j) {
            xs[j]      = c0[j];
            xs[4 + j]  = c1[j];
            xs[8 + j]  = c2[j];
            xs[12 + j] = c3[j];
        }
        bf16x8 ah[2], al[2];
#pragma unroll
        for (int s = 0; s < 2; ++s)
#pragma unroll
            for (int j = 0; j < 8; ++j) {
                float v = xs[s * 8 + j];
                short hh = f2bf(v);
                ah[s][j] = hh;
                al[s][j] = f2bf(v - bf2f(hh));
            }

        // ---- layer 1: two N-tiles, two K-steps, 3-pass ----
        f32x4 acc0 = {0.f, 0.f, 0.f, 0.f};
        f32x4 acc1 = {0.f, 0.f, 0.f, 0.f};
#pragma unroll
        for (int s = 0; s < 2; ++s) {
            acc0 = __builtin_amdgcn_mfma_f32_16x16x32_bf16(ah[s], w1h[s][0], acc0, 0, 0, 0);
            acc0 = __builtin_amdgcn_mfma_f32_16x16x32_bf16(al[s], w1h[s][0], acc0, 0, 0, 0);
            acc0 = __builtin_amdgcn_mfma_f32_16x16x32_bf16(ah[s], w1l[s][0], acc0, 0, 0, 0);
            acc1 = __builtin_amdgcn_mfma_f32_16x16x32_bf16(ah[s], w1h[s][1], acc1, 0, 0, 0);
            acc1 = __builtin_amdgcn_mfma_f32_16x16x32_bf16(al[s], w1h[s][1], acc1, 0, 0, 0);
            acc1 = __builtin_amdgcn_mfma_f32_16x16x32_bf16(ah[s], w1l[s][1], acc1, 0, 0, 0);
        }

        // ---- h: C-layout -> LDS -> A-layout ----
#pragma unroll
        for (int r = 0; r < 4; ++r) {
            hw[(q * 4 + r) * LSTR + l15]      = acc0[r];
            hw[(q * 4 + r) * LSTR + 16 + l15] = acc1[r];
        }
        asm volatile("s_waitcnt lgkmcnt(0)" ::: "memory");
        __builtin_amdgcn_wave_barrier();

        float hv[8];
#pragma unroll
        for (int j = 0; j < 8; ++j) hv[j] = hw[l15 * LSTR + q * 8 + j];

        bf16x8 fh, fl;
#pragma unroll
        for (int j = 0; j < 8; ++j) {
            float v = fmaxf(hv[j] + b1v[j], 0.0f);   // bias + relu in fp32
            short hh = f2bf(v);
            fh[j] = hh;
            fl[j] = f2bf(v - bf2f(hh));
        }
        __builtin_amdgcn_wave_barrier();   // reads done before next iter's writes

        // ---- layer 2 ----
        f32x4 acc2 = {0.f, 0.f, 0.f, 0.f};
        acc2 = __builtin_amdgcn_mfma_f32_16x16x32_bf16(fh, w2h, acc2, 0, 0, 0);
        acc2 = __builtin_amdgcn_mfma_f32_16x16x32_bf16(fl, w2h, acc2, 0, 0, 0);
        acc2 = __builtin_amdgcn_mfma_f32_16x16x32_bf16(fh, w2l, acc2, 0, 0, 0);

        // ---- store y: lane writes rows q*4+r, col l15 ----
        float* yr = y + (size_t)(tile0 + t) * 256 + q * 64 + l15;
#pragma unroll
        for (int r = 0; r < 4; ++r) yr[r * 16] = acc2[r] + b2v;

        c0 = n0; c1 = n1; c2 = n2; c3 = n3;
    }
}

extern "C" void kernel_launch(void* const* d_in, const int* in_sizes, int n_in,
                              void* d_out, int out_size, void* d_ws, size_t ws_size,
                              hipStream_t stream) {
    const float* x  = (const float*)d_in[0];
    const float* W1 = (const float*)d_in[1];
    const float* b1 = (const float*)d_in[2];
    const float* W2 = (const float*)d_in[3];
    const float* b2 = (const float*)d_in[4];
    float* yp = (float*)d_out;

    const int nrows = in_sizes[0] / 64;            // 1048576
    const int rows_per_block = 4 * TPW * 16;       // 512
    const int grid = nrows / rows_per_block;       // 2048
    livenet_mlp_mfma<<<grid, BLOCK, 0, stream>>>(x, W1, b1, W2, b2, yp);
}